// Round 8
// baseline (83.990 us; speedup 1.0000x reference)
//
#include <hip/hip_runtime.h>

#define L_LEN   262144
#define OUT_LEN 262142
#define BATCH   32
#define NTOT    (32.0 * 262142.0)

typedef float v4f __attribute__((ext_vector_type(4)));

struct KPtrs { const float* p[12]; };

// ============ K0: pooled[256] = mean over 1024-elem bins of x[0] ============
__global__ void pool_kernel(const float* __restrict__ x, float* __restrict__ pooled) {
    int bin = blockIdx.x;          // 256 blocks
    int tid = threadIdx.x;         // 256 threads
    const float4* x4 = (const float4*)(x + bin * 1024);
    float4 v = x4[tid];
    float sum = v.x + v.y + v.z + v.w;
    #pragma unroll
    for (int off = 32; off; off >>= 1) sum += __shfl_down(sum, off);
    __shared__ float wred[4];
    int wave = tid >> 6;
    if ((tid & 63) == 0) wred[wave] = sum;
    __syncthreads();
    if (tid == 0)
        pooled[bin] = (wred[0] + wred[1] + wred[2] + wred[3]) * (1.0f / 1024.0f);
}

// ============ K1: stats (blocks 0..1023) ∥ attention MLP (block 1024) ============
// Stats: block handles 4 consecutive 2048-tiles (128 tiles/row, 4096 total).
// X = sum(x), R_l = sum(x_u*x_{u+l}) l=0..10, row-local (zero-pad past row end).
// part SoA: part[v*1024 + block], v=0 -> X, v=1+l -> R_l.
// MLP block: pooled -> Linear+ReLU -> Linear -> softmax -> Kraw[220]
// (Kraw layout: [5 classes][4 ch][11 taps], class q = kernels with k <= 2q+3).
__global__ __launch_bounds__(256, 4) void stats_mlp_kernel(const float* __restrict__ x,
                                                           const float* __restrict__ w1,
                                                           const float* __restrict__ b1,
                                                           const float* __restrict__ w2,
                                                           const float* __restrict__ b2,
                                                           KPtrs kp,
                                                           const float* __restrict__ pooled,
                                                           float* __restrict__ part,
                                                           float* __restrict__ Kraw) {
    int tid = threadIdx.x;

    if (blockIdx.x == 1024) {
        // ---- attention MLP (runs concurrently with stats blocks) ----
        __shared__ float h[128];
        __shared__ float logits[12];
        __shared__ float s[12];
        int w = tid >> 6, lane = tid & 63;
        float4 pv = ((const float4*)pooled)[lane];
        // layer 1: wave w rows 32w .. 32w+31
        for (int i = 0; i < 32; ++i) {
            int t = w * 32 + i;
            float4 wv = ((const float4*)(w1 + t * 256))[lane];
            float p = wv.x * pv.x + wv.y * pv.y + wv.z * pv.z + wv.w * pv.w;
            #pragma unroll
            for (int off = 32; off; off >>= 1) p += __shfl_down(p, off);
            if (lane == 0) h[t] = fmaxf(p + b1[t], 0.0f);
        }
        __syncthreads();
        // layer 2: wave w rows f = w, w+4, w+8
        for (int f = w; f < 12; f += 4) {
            float2 wv = ((const float2*)(w2 + f * 128))[lane];
            float p = wv.x * h[2 * lane] + wv.y * h[2 * lane + 1];
            #pragma unroll
            for (int off = 32; off; off >>= 1) p += __shfl_down(p, off);
            if (lane == 0) logits[f] = p + b2[f];
        }
        __syncthreads();
        if (tid == 0) {
            float m = logits[0];
            #pragma unroll
            for (int i = 1; i < 12; ++i) m = fmaxf(m, logits[i]);
            float e[12]; float sum = 0.0f;
            #pragma unroll
            for (int i = 0; i < 12; ++i) { e[i] = expf(logits[i] - m); sum += e[i]; }
            float inv = 1.0f / sum;
            #pragma unroll
            for (int i = 0; i < 12; ++i) s[i] = e[i] * inv;
        }
        __syncthreads();
        constexpr int KSa[12] = {3,3,3,5,5,7,7,7,9,9,11,11};
        if (tid < 220) {
            int q = tid / 44, r = tid % 44, c = r / 11, j = r % 11;
            int kmax = 2 * q + 3;
            float v = 0.0f;
            #pragma unroll
            for (int i = 0; i < 12; ++i) {
                int k = KSa[i];
                if (k <= kmax && j < k) v = fmaf(s[i], kp.p[i][c * k + j], v);
            }
            Kraw[tid] = v;
        }
        return;
    }

    // ---- stats path ----
    __shared__ float xt[2064];
    float X = 0.0f, R[11];
    #pragma unroll
    for (int l = 0; l < 11; ++l) R[l] = 0.0f;

    for (int it = 0; it < 4; ++it) {
        int T = blockIdx.x * 4 + it;       // 0..4095
        int row = T >> 7, seg = T & 127;   // row 0..31, seg 0..127
        int base = seg << 11;
        const float* xb = x + row * L_LEN;
        *(float4*)&xt[4 * tid]        = *(const float4*)(xb + base + 4 * tid);
        *(float4*)&xt[1024 + 4 * tid] = *(const float4*)(xb + base + 1024 + 4 * tid);
        if (tid < 3) {
            float4 v = {0.f, 0.f, 0.f, 0.f};
            if (seg < 127) v = *(const float4*)(xb + base + 2048 + 4 * tid);
            *(float4*)&xt[2048 + 4 * tid] = v;
        }
        __syncthreads();

        float xv[18];
        const float4* xr = (const float4*)&xt[8 * tid];
        #pragma unroll
        for (int i = 0; i < 4; ++i) {
            float4 a = xr[i];
            xv[4*i] = a.x; xv[4*i+1] = a.y; xv[4*i+2] = a.z; xv[4*i+3] = a.w;
        }
        float2 a4 = *(const float2*)&xt[8 * tid + 16];
        xv[16] = a4.x; xv[17] = a4.y;

        float s8 = 0.0f;
        #pragma unroll
        for (int p = 0; p < 8; ++p) s8 += xv[p];
        X += s8;
        #pragma unroll
        for (int l = 0; l < 11; ++l) {
            float r = 0.0f;
            #pragma unroll
            for (int p = 0; p < 8; ++p) r = fmaf(xv[p], xv[p + l], r);
            R[l] += r;
        }
        __syncthreads();
    }

    // block-reduce 12 values -> part
    #pragma unroll
    for (int off = 32; off; off >>= 1) {
        X += __shfl_down(X, off);
        #pragma unroll
        for (int l = 0; l < 11; ++l) R[l] += __shfl_down(R[l], off);
    }
    __shared__ float red[4][12];
    int wave = tid >> 6;
    if ((tid & 63) == 0) {
        red[wave][0] = X;
        #pragma unroll
        for (int l = 0; l < 11; ++l) red[wave][1 + l] = R[l];
    }
    __syncthreads();
    if (tid < 12)
        part[tid * 1024 + blockIdx.x] = red[0][tid] + red[1][tid] + red[2][tid] + red[3][tid];
}

// ============ K2: fold — reduce partials + BN fold into taps/bias ============
// 1 block x 256 threads (~2 us).
__global__ void fold_kernel(const float* __restrict__ part,
                            const float* __restrict__ Kraw,
                            const float* __restrict__ gamma, const float* __restrict__ beta,
                            float* __restrict__ Kscl, float* __restrict__ biasv) {
    __shared__ double vals[12];
    __shared__ float Kr[220];
    __shared__ float g[4];
    int tid = threadIdx.x;
    int w = tid >> 6, lane = tid & 63;
    if (tid < 220) Kr[tid] = Kraw[tid];
    for (int v = w; v < 12; v += 4) {
        double d = 0.0;
        #pragma unroll 4
        for (int i = 0; i < 16; ++i) d += (double)part[v * 1024 + i * 64 + lane];
        #pragma unroll
        for (int off = 32; off; off >>= 1) d += __shfl_down(d, off);
        if (lane == 0) vals[v] = d;
    }
    __syncthreads();
    if (tid < 4) {
        int c = tid;
        const float* Kc = Kr + 4 * 44 + c * 11;   // full-kernel class
        double sK = 0.0;
        for (int j = 0; j < 11; ++j) sK += (double)Kc[j];
        double mean = sK * vals[0] / NTOT;
        double ex2 = 0.0;
        for (int l = 0; l < 11; ++l) {
            double A = 0.0;
            for (int j = 0; j + l < 11; ++j) A += (double)Kc[j] * (double)Kc[j + l];
            ex2 += (l ? 2.0 : 1.0) * A * vals[1 + l];
        }
        ex2 /= NTOT;
        double var = ex2 - mean * mean;
        float gg = gamma[c] * (float)(1.0 / sqrt(var + 1e-5));
        g[c] = gg;
        biasv[c] = beta[c] - (float)mean * gg;
    }
    __syncthreads();
    if (tid < 220) {
        int c = (tid / 11) % 4;
        Kscl[tid] = Kr[tid] * g[c];
    }
}

// ============ K3: write pass — 2048-tile, lane-contiguous dwordx4 stores ============
// grid 4096 = 32 rows x 128 segs. Thread = 4 consecutive outputs x 2 half-tiles x 4 ch.
// Odd channels shifted +2 (row base ≡ 2 mod 4) so every store is 16B-aligned dwordx4
// with 16B lane stride (wave writes 1KB contiguous). Head/tail scalar fixups.
__global__ __launch_bounds__(256, 4) void write_kernel(const float* __restrict__ x,
                                                       const float* __restrict__ Kscl,
                                                       const float* __restrict__ biasv,
                                                       float* __restrict__ out) {
    __shared__ float xt[2064];
    int tid = threadIdx.x;
    int b = blockIdx.x >> 7, seg = blockIdx.x & 127;
    int base = seg << 11;
    const float* xb = x + b * L_LEN;

    *(float4*)&xt[4 * tid]        = *(const float4*)(xb + base + 4 * tid);
    *(float4*)&xt[1024 + 4 * tid] = *(const float4*)(xb + base + 1024 + 4 * tid);
    if (tid < 4) {
        float4 v = {0.f, 0.f, 0.f, 0.f};
        if (seg < 127) v = *(const float4*)(xb + base + 2048 + 4 * tid);
        *(float4*)&xt[2048 + 4 * tid] = v;
    }

    float K[4][11], bias[4];
    #pragma unroll
    for (int c = 0; c < 4; ++c) {
        #pragma unroll
        for (int j = 0; j < 11; ++j) K[c][j] = Kscl[4 * 44 + c * 11 + j];
        bias[c] = biasv[c];
    }
    __syncthreads();

    #pragma unroll
    for (int gdx = 0; gdx < 2; ++gdx) {
        int lt = gdx * 1024 + 4 * tid;
        bool scalar = (seg == 127) && (gdx == 1) && (tid >= 253);
        if (!scalar) {
            float xv[16];
            const float4* xr = (const float4*)&xt[lt];
            #pragma unroll
            for (int i = 0; i < 4; ++i) {
                float4 a = xr[i];
                xv[4*i] = a.x; xv[4*i+1] = a.y; xv[4*i+2] = a.z; xv[4*i+3] = a.w;
            }
            #pragma unroll
            for (int c = 0; c < 4; ++c) {
                int sh = (c & 1) ? 2 : 0;
                float v[4];
                #pragma unroll
                for (int p = 0; p < 4; ++p) {
                    float a = bias[c];
                    #pragma unroll
                    for (int j = 0; j < 11; ++j) a = fmaf(K[c][j], xv[sh + p + j], a);
                    v[p] = fmaxf(a, 0.0f);
                }
                float* op = out + (size_t)(4 * b + c) * OUT_LEN + base + sh + lt;
                *(v4f*)op = (v4f){v[0], v[1], v[2], v[3]};
            }
        } else {
            #pragma unroll
            for (int par = 0; par < 2; ++par) {
                int sh = 2 * par;
                for (int p = 0; p < 4; ++p) {
                    int t = base + sh + lt + p;
                    if (t >= OUT_LEN) continue;
                    int rem = L_LEN - t;
                    int q = (rem - 3) >> 1; if (q > 4) q = 4;
                    int kmax = 2 * q + 3;
                    int li = sh + lt + p;
                    for (int c = par; c < 4; c += 2) {
                        float a = bias[c];
                        for (int j = 0; j < kmax; ++j) a = fmaf(Kscl[q * 44 + c * 11 + j], xt[li + j], a);
                        out[(size_t)(4 * b + c) * OUT_LEN + t] = fmaxf(a, 0.0f);
                    }
                }
            }
        }
    }
    // head: odd channels' outputs t=0,1 (not covered by shifted quads)
    if (seg == 0 && tid == 0) {
        for (int c = 1; c < 4; c += 2) {
            for (int t = 0; t < 2; ++t) {
                float a = bias[c];
                #pragma unroll
                for (int j = 0; j < 11; ++j) a = fmaf(K[c][j], xt[t + j], a);
                out[(size_t)(4 * b + c) * OUT_LEN + t] = fmaxf(a, 0.0f);
            }
        }
    }
}

extern "C" void kernel_launch(void* const* d_in, const int* in_sizes, int n_in,
                              void* d_out, int out_size, void* d_ws, size_t ws_size,
                              hipStream_t stream) {
    const float* x     = (const float*)d_in[0];
    const float* w1    = (const float*)d_in[1];
    const float* b1    = (const float*)d_in[2];
    const float* w2    = (const float*)d_in[3];
    const float* b2    = (const float*)d_in[4];
    const float* gamma = (const float*)d_in[5];
    const float* beta  = (const float*)d_in[6];
    KPtrs kp;
    for (int i = 0; i < 12; ++i) kp.p[i] = (const float*)d_in[7 + i];
    float* out = (float*)d_out;

    char* ws = (char*)d_ws;
    float* pooled = (float*)(ws + 0);       // 256 floats
    float* Kraw   = (float*)(ws + 1024);    // 220 floats
    float* Kscl   = (float*)(ws + 2048);    // 220 floats
    float* biasv  = (float*)(ws + 3072);    // 4 floats
    float* part   = (float*)(ws + 4096);    // 12*1024 floats = 48 KB

    pool_kernel<<<dim3(256), dim3(256), 0, stream>>>(x, pooled);
    stats_mlp_kernel<<<dim3(1025), dim3(256), 0, stream>>>(x, w1, b1, w2, b2, kp,
                                                           pooled, part, Kraw);
    fold_kernel<<<dim3(1), dim3(256), 0, stream>>>(part, Kraw, gamma, beta, Kscl, biasv);
    write_kernel<<<dim3(4096), dim3(256), 0, stream>>>(x, Kscl, biasv, out);
}

// Round 9
// 80.838 us; speedup vs baseline: 1.0390x; 1.0390x over previous
//
#include <hip/hip_runtime.h>

#define L_LEN   262144
#define OUT_LEN 262142
#define BATCH   32
#define NTOT    (32.0 * 262142.0)

typedef float v4f __attribute__((ext_vector_type(4)));

struct KPtrs { const float* p[12]; };

// ============ K0: pooled[256] = mean over 1024-elem bins of x[0] ============
__global__ void pool_kernel(const float* __restrict__ x, float* __restrict__ pooled) {
    int bin = blockIdx.x;          // 256 blocks
    int tid = threadIdx.x;         // 256 threads
    const float4* x4 = (const float4*)(x + bin * 1024);
    float4 v = x4[tid];
    float sum = v.x + v.y + v.z + v.w;
    #pragma unroll
    for (int off = 32; off; off >>= 1) sum += __shfl_down(sum, off);
    __shared__ float wred[4];
    int wave = tid >> 6;
    if ((tid & 63) == 0) wred[wave] = sum;
    __syncthreads();
    if (tid == 0)
        pooled[bin] = (wred[0] + wred[1] + wred[2] + wred[3]) * (1.0f / 1024.0f);
}

// ============ K1: MLP (block 0, dispatched FIRST -> fully overlapped) ∥ stats (blocks 1..1024) ============
// Stats: block handles 4 consecutive 2048-tiles (128 tiles/row, 4096 total).
// X = sum(x), R_l = sum(x_u*x_{u+l}) l=0..10, row-local (zero-pad past row end).
// part SoA: part[v*1024 + (blk-1)], v=0 -> X, v=1+l -> R_l.
// MLP block: pooled -> Linear+ReLU -> Linear -> softmax -> Kraw[220]
// (Kraw layout: [5 classes][4 ch][11 taps], class q = kernels with k <= 2q+3).
__global__ __launch_bounds__(256, 4) void stats_mlp_kernel(const float* __restrict__ x,
                                                           const float* __restrict__ w1,
                                                           const float* __restrict__ b1,
                                                           const float* __restrict__ w2,
                                                           const float* __restrict__ b2,
                                                           KPtrs kp,
                                                           const float* __restrict__ pooled,
                                                           float* __restrict__ part,
                                                           float* __restrict__ Kraw) {
    int tid = threadIdx.x;

    if (blockIdx.x == 0) {
        // ---- attention MLP (block 0: resident from t=0, hides under stats) ----
        __shared__ float h[128];
        __shared__ float logits[12];
        __shared__ float s[12];
        int w = tid >> 6, lane = tid & 63;
        float4 pv = ((const float4*)pooled)[lane];
        // layer 1: wave w rows 32w .. 32w+31
        for (int i = 0; i < 32; ++i) {
            int t = w * 32 + i;
            float4 wv = ((const float4*)(w1 + t * 256))[lane];
            float p = wv.x * pv.x + wv.y * pv.y + wv.z * pv.z + wv.w * pv.w;
            #pragma unroll
            for (int off = 32; off; off >>= 1) p += __shfl_down(p, off);
            if (lane == 0) h[t] = fmaxf(p + b1[t], 0.0f);
        }
        __syncthreads();
        // layer 2: wave w rows f = w, w+4, w+8
        for (int f = w; f < 12; f += 4) {
            float2 wv = ((const float2*)(w2 + f * 128))[lane];
            float p = wv.x * h[2 * lane] + wv.y * h[2 * lane + 1];
            #pragma unroll
            for (int off = 32; off; off >>= 1) p += __shfl_down(p, off);
            if (lane == 0) logits[f] = p + b2[f];
        }
        __syncthreads();
        if (tid == 0) {
            float m = logits[0];
            #pragma unroll
            for (int i = 1; i < 12; ++i) m = fmaxf(m, logits[i]);
            float e[12]; float sum = 0.0f;
            #pragma unroll
            for (int i = 0; i < 12; ++i) { e[i] = expf(logits[i] - m); sum += e[i]; }
            float inv = 1.0f / sum;
            #pragma unroll
            for (int i = 0; i < 12; ++i) s[i] = e[i] * inv;
        }
        __syncthreads();
        constexpr int KSa[12] = {3,3,3,5,5,7,7,7,9,9,11,11};
        if (tid < 220) {
            int q = tid / 44, r = tid % 44, c = r / 11, j = r % 11;
            int kmax = 2 * q + 3;
            float v = 0.0f;
            #pragma unroll
            for (int i = 0; i < 12; ++i) {
                int k = KSa[i];
                if (k <= kmax && j < k) v = fmaf(s[i], kp.p[i][c * k + j], v);
            }
            Kraw[tid] = v;
        }
        return;
    }

    // ---- stats path (blocks 1..1024) ----
    __shared__ float xt[2064];
    float X = 0.0f, R[11];
    #pragma unroll
    for (int l = 0; l < 11; ++l) R[l] = 0.0f;

    for (int it = 0; it < 4; ++it) {
        int T = (blockIdx.x - 1) * 4 + it; // 0..4095
        int row = T >> 7, seg = T & 127;   // row 0..31, seg 0..127
        int base = seg << 11;
        const float* xb = x + row * L_LEN;
        *(float4*)&xt[4 * tid]        = *(const float4*)(xb + base + 4 * tid);
        *(float4*)&xt[1024 + 4 * tid] = *(const float4*)(xb + base + 1024 + 4 * tid);
        if (tid < 3) {
            float4 v = {0.f, 0.f, 0.f, 0.f};
            if (seg < 127) v = *(const float4*)(xb + base + 2048 + 4 * tid);
            *(float4*)&xt[2048 + 4 * tid] = v;
        }
        __syncthreads();

        float xv[18];
        const float4* xr = (const float4*)&xt[8 * tid];
        #pragma unroll
        for (int i = 0; i < 4; ++i) {
            float4 a = xr[i];
            xv[4*i] = a.x; xv[4*i+1] = a.y; xv[4*i+2] = a.z; xv[4*i+3] = a.w;
        }
        float2 a4 = *(const float2*)&xt[8 * tid + 16];
        xv[16] = a4.x; xv[17] = a4.y;

        float s8 = 0.0f;
        #pragma unroll
        for (int p = 0; p < 8; ++p) s8 += xv[p];
        X += s8;
        #pragma unroll
        for (int l = 0; l < 11; ++l) {
            float r = 0.0f;
            #pragma unroll
            for (int p = 0; p < 8; ++p) r = fmaf(xv[p], xv[p + l], r);
            R[l] += r;
        }
        __syncthreads();
    }

    // block-reduce 12 values -> part
    #pragma unroll
    for (int off = 32; off; off >>= 1) {
        X += __shfl_down(X, off);
        #pragma unroll
        for (int l = 0; l < 11; ++l) R[l] += __shfl_down(R[l], off);
    }
    __shared__ float red[4][12];
    int wave = tid >> 6;
    if ((tid & 63) == 0) {
        red[wave][0] = X;
        #pragma unroll
        for (int l = 0; l < 11; ++l) red[wave][1 + l] = R[l];
    }
    __syncthreads();
    if (tid < 12)
        part[tid * 1024 + (blockIdx.x - 1)] = red[0][tid] + red[1][tid] + red[2][tid] + red[3][tid];
}

// ============ K2: fold — reduce partials + BN fold into taps/bias ============
// 1 block x 256 threads (~1.5 us).
__global__ void fold_kernel(const float* __restrict__ part,
                            const float* __restrict__ Kraw,
                            const float* __restrict__ gamma, const float* __restrict__ beta,
                            float* __restrict__ Kscl, float* __restrict__ biasv) {
    __shared__ double vals[12];
    __shared__ float Kr[220];
    __shared__ float g[4];
    int tid = threadIdx.x;
    int w = tid >> 6, lane = tid & 63;
    if (tid < 220) Kr[tid] = Kraw[tid];
    for (int v = w; v < 12; v += 4) {
        double d = 0.0;
        #pragma unroll 4
        for (int i = 0; i < 16; ++i) d += (double)part[v * 1024 + i * 64 + lane];
        #pragma unroll
        for (int off = 32; off; off >>= 1) d += __shfl_down(d, off);
        if (lane == 0) vals[v] = d;
    }
    __syncthreads();
    if (tid < 4) {
        int c = tid;
        const float* Kc = Kr + 4 * 44 + c * 11;   // full-kernel class
        double sK = 0.0;
        for (int j = 0; j < 11; ++j) sK += (double)Kc[j];
        double mean = sK * vals[0] / NTOT;
        double ex2 = 0.0;
        for (int l = 0; l < 11; ++l) {
            double A = 0.0;
            for (int j = 0; j + l < 11; ++j) A += (double)Kc[j] * (double)Kc[j + l];
            ex2 += (l ? 2.0 : 1.0) * A * vals[1 + l];
        }
        ex2 /= NTOT;
        double var = ex2 - mean * mean;
        float gg = gamma[c] * (float)(1.0 / sqrt(var + 1e-5));
        g[c] = gg;
        biasv[c] = beta[c] - (float)mean * gg;
    }
    __syncthreads();
    if (tid < 220) {
        int c = (tid / 11) % 4;
        Kscl[tid] = Kr[tid] * g[c];
    }
}

// ============ K3: write pass — 2048-tile, lane-contiguous dwordx4 stores ============
// grid 4096 = 32 rows x 128 segs. Thread = 4 consecutive outputs x 2 half-tiles x 4 ch.
// Odd channels shifted +2 (row base ≡ 2 mod 4) so every store is 16B-aligned dwordx4
// with 16B lane stride (wave writes 1KB contiguous). Head/tail scalar fixups.
__global__ __launch_bounds__(256, 4) void write_kernel(const float* __restrict__ x,
                                                       const float* __restrict__ Kscl,
                                                       const float* __restrict__ biasv,
                                                       float* __restrict__ out) {
    __shared__ float xt[2064];
    int tid = threadIdx.x;
    int b = blockIdx.x >> 7, seg = blockIdx.x & 127;
    int base = seg << 11;
    const float* xb = x + b * L_LEN;

    *(float4*)&xt[4 * tid]        = *(const float4*)(xb + base + 4 * tid);
    *(float4*)&xt[1024 + 4 * tid] = *(const float4*)(xb + base + 1024 + 4 * tid);
    if (tid < 4) {
        float4 v = {0.f, 0.f, 0.f, 0.f};
        if (seg < 127) v = *(const float4*)(xb + base + 2048 + 4 * tid);
        *(float4*)&xt[2048 + 4 * tid] = v;
    }

    float K[4][11], bias[4];
    #pragma unroll
    for (int c = 0; c < 4; ++c) {
        #pragma unroll
        for (int j = 0; j < 11; ++j) K[c][j] = Kscl[4 * 44 + c * 11 + j];
        bias[c] = biasv[c];
    }
    __syncthreads();

    #pragma unroll
    for (int gdx = 0; gdx < 2; ++gdx) {
        int lt = gdx * 1024 + 4 * tid;
        bool scalar = (seg == 127) && (gdx == 1) && (tid >= 253);
        if (!scalar) {
            float xv[16];
            const float4* xr = (const float4*)&xt[lt];
            #pragma unroll
            for (int i = 0; i < 4; ++i) {
                float4 a = xr[i];
                xv[4*i] = a.x; xv[4*i+1] = a.y; xv[4*i+2] = a.z; xv[4*i+3] = a.w;
            }
            #pragma unroll
            for (int c = 0; c < 4; ++c) {
                int sh = (c & 1) ? 2 : 0;
                float v[4];
                #pragma unroll
                for (int p = 0; p < 4; ++p) {
                    float a = bias[c];
                    #pragma unroll
                    for (int j = 0; j < 11; ++j) a = fmaf(K[c][j], xv[sh + p + j], a);
                    v[p] = fmaxf(a, 0.0f);
                }
                float* op = out + (size_t)(4 * b + c) * OUT_LEN + base + sh + lt;
                *(v4f*)op = (v4f){v[0], v[1], v[2], v[3]};
            }
        } else {
            #pragma unroll
            for (int par = 0; par < 2; ++par) {
                int sh = 2 * par;
                for (int p = 0; p < 4; ++p) {
                    int t = base + sh + lt + p;
                    if (t >= OUT_LEN) continue;
                    int rem = L_LEN - t;
                    int q = (rem - 3) >> 1; if (q > 4) q = 4;
                    int kmax = 2 * q + 3;
                    int li = sh + lt + p;
                    for (int c = par; c < 4; c += 2) {
                        float a = bias[c];
                        for (int j = 0; j < kmax; ++j) a = fmaf(Kscl[q * 44 + c * 11 + j], xt[li + j], a);
                        out[(size_t)(4 * b + c) * OUT_LEN + t] = fmaxf(a, 0.0f);
                    }
                }
            }
        }
    }
    // head: odd channels' outputs t=0,1 (not covered by shifted quads)
    if (seg == 0 && tid == 0) {
        for (int c = 1; c < 4; c += 2) {
            for (int t = 0; t < 2; ++t) {
                float a = bias[c];
                #pragma unroll
                for (int j = 0; j < 11; ++j) a = fmaf(K[c][j], xt[t + j], a);
                out[(size_t)(4 * b + c) * OUT_LEN + t] = fmaxf(a, 0.0f);
            }
        }
    }
}

extern "C" void kernel_launch(void* const* d_in, const int* in_sizes, int n_in,
                              void* d_out, int out_size, void* d_ws, size_t ws_size,
                              hipStream_t stream) {
    const float* x     = (const float*)d_in[0];
    const float* w1    = (const float*)d_in[1];
    const float* b1    = (const float*)d_in[2];
    const float* w2    = (const float*)d_in[3];
    const float* b2    = (const float*)d_in[4];
    const float* gamma = (const float*)d_in[5];
    const float* beta  = (const float*)d_in[6];
    KPtrs kp;
    for (int i = 0; i < 12; ++i) kp.p[i] = (const float*)d_in[7 + i];
    float* out = (float*)d_out;

    char* ws = (char*)d_ws;
    float* pooled = (float*)(ws + 0);       // 256 floats
    float* Kraw   = (float*)(ws + 1024);    // 220 floats
    float* Kscl   = (float*)(ws + 2048);    // 220 floats
    float* biasv  = (float*)(ws + 3072);    // 4 floats
    float* part   = (float*)(ws + 4096);    // 12*1024 floats = 48 KB

    pool_kernel<<<dim3(256), dim3(256), 0, stream>>>(x, pooled);
    stats_mlp_kernel<<<dim3(1025), dim3(256), 0, stream>>>(x, w1, b1, w2, b2, kp,
                                                           pooled, part, Kraw);
    fold_kernel<<<dim3(1), dim3(256), 0, stream>>>(part, Kraw, gamma, beta, Kscl, biasv);
    write_kernel<<<dim3(4096), dim3(256), 0, stream>>>(x, Kscl, biasv, out);
}